// Round 1
// baseline (83.465 us; speedup 1.0000x reference)
//
#include <hip/hip_runtime.h>

// DGCLoss: 1 - mean NDCG. N=384 rows, D=256 feats, M=383 off-diag cols.
//
// Round 15: collapse to 2 kernels. dgc_normT is gone: each fused thread
// (r, j) reads raw row j in full for the gram dot anyway, so the row norm
// Sum(x^2) is a free by-product (cos = dot_raw * invn_i * invn_j). The idcg
// table is per-block too (only 2 gv values needed), computed on the 10 waves
// that idle during the hist prefix-scan. Removes: the 25-block underutilized
// normT kernel, its drain boundary, one graph launch, XT/XN round-trips, and
// the 24.6 KB pacc staging + reduce phase.
//   dgc_fused : block = rows (2b,2b+1): raw gram + inline norms -> 2 srows,
//               per-block idcg, counting sorts, pair-rcp soft window,
//               ndcg[n] stores.
//   dgc_final : 1 block: out = 1 - mean(ndcg).

#define NN 384
#define DD 256
#define MM 383
// exp(-d*1000) == exp2(s_i - s_j) with s = ((cos+1)*0.5) * 1000*log2(e)
#define HSCALE 721.3475204444817f   // 0.5 * 1000 * log2(e)
#define NBUCK  256
#define BSCALE 0.1767955801104972f  // 256 / 1448  (values in [0, 1442.7])
#define WWIN   6.0f                 // soft-window half-width in s-units

__global__ __launch_bounds__(768) void dgc_fused(const float* __restrict__ x,
                                                 const int* __restrict__ gt,
                                                 float* __restrict__ ndcg) {
    __shared__ float xs[2][DD];         // raw rows n0, n0+1
    __shared__ float invn[NN];          // 1/||row j||
    __shared__ float srow[2][NN];
    __shared__ float vsort[2][NN];
    __shared__ int   sidx[2][NN];
    __shared__ int   hist[2][NBUCK];
    __shared__ int   pre[2][NBUCK + 1];
    __shared__ int   cnt[6];
    __shared__ int   cum[2][6];
    __shared__ float redd[12];
    __shared__ float idr[12][2];        // per-wave idcg partials (waves 0,6 stay 0)

    const int n0   = blockIdx.x * 2;
    const int t    = threadIdx.x;
    const int lane = t & 63;
    const int wave = t >> 6;
    const int r    = t / 384;           // row-half: waves 0-5 -> 0, 6-11 -> 1
    const int u    = t - r * 384;       // column j, 0..383

    // ---- S0: init ----
    if (t < 128)
        ((float4*)xs[t >> 6])[t & 63] =
            ((const float4*)(x + (size_t)(n0 + (t >> 6)) * DD))[t & 63];
    if (t < 512) ((int*)hist)[t] = 0;
    if (t < 6)  cnt[t] = 0;
    if (t < 24) ((float*)idr)[t] = 0.0f;
    __syncthreads();

    // ---- S1: gt histogram + raw gram dot (and inline row norms on r0) ----
    if (t < NN) atomicAdd(&cnt[gt[t]], 1);

    float dot;
    {
        const float4* xrow = (const float4*)(x + (size_t)u * DD);
        const float4* xsr  = (const float4*)xs[r];
        float4 ad = {0.f, 0.f, 0.f, 0.f};
        if (r == 0) {                    // wave-uniform branch
            float4 as = {0.f, 0.f, 0.f, 0.f};
            #pragma unroll 8
            for (int k4 = 0; k4 < 64; ++k4) {
                float4 bv = xrow[k4];
                float4 av = xsr[k4];     // LDS broadcast, conflict-free
                ad.x = fmaf(av.x, bv.x, ad.x); ad.y = fmaf(av.y, bv.y, ad.y);
                ad.z = fmaf(av.z, bv.z, ad.z); ad.w = fmaf(av.w, bv.w, ad.w);
                as.x = fmaf(bv.x, bv.x, as.x); as.y = fmaf(bv.y, bv.y, as.y);
                as.z = fmaf(bv.z, bv.z, as.z); as.w = fmaf(bv.w, bv.w, as.w);
            }
            const float sq = (as.x + as.y) + (as.z + as.w);
            invn[u] = __builtin_amdgcn_rsqf(fmaxf(sq, 1e-16f));
        } else {
            #pragma unroll 8
            for (int k4 = 0; k4 < 64; ++k4) {
                float4 bv = xrow[k4];
                float4 av = xsr[k4];
                ad.x = fmaf(av.x, bv.x, ad.x); ad.y = fmaf(av.y, bv.y, ad.y);
                ad.z = fmaf(av.z, bv.z, ad.z); ad.w = fmaf(av.w, bv.w, ad.w);
            }
        }
        dot = (ad.x + ad.y) + (ad.z + ad.w);
    }
    __syncthreads();

    // ---- S2: cum tables (threads 0,1) + srow + counting-sort bucket ----
    if (t < 2) {
        const int gv = gt[n0 + t];
        int h[6];
        #pragma unroll
        for (int g = 0; g < 6; ++g) h[g] = 0;
        #pragma unroll
        for (int v = 0; v < 6; ++v) {
            int d = v - gv; d = d < 0 ? -d : d;
            h[d] += cnt[v];
        }
        h[0] -= 1;                       // remove self term
        int s = 0;
        #pragma unroll
        for (int g = 0; g < 6; ++g) { s += h[g]; cum[t][g] = s; }
    }

    const float cosn = dot * invn[u] * invn[n0 + r];
    const float vraw = fmaf(cosn, HSCALE, HSCALE);
    srow[r][u] = vraw;
    int b = (int)(vraw * BSCALE);
    b = b < 0 ? 0 : (b > NBUCK - 1 ? NBUCK - 1 : b);
    const int slot = atomicAdd(&hist[r][b], 1);
    __syncthreads();

    // ---- S3: hist scan (waves 0,6) || per-block idcg p-loop (other waves) ----
    if (wave == 0 || wave == 6) {
        const int rr = wave / 6;
        const int s0 = hist[rr][lane * 4 + 0], s1 = hist[rr][lane * 4 + 1];
        const int s2 = hist[rr][lane * 4 + 2], s3 = hist[rr][lane * 4 + 3];
        const int sum = s0 + s1 + s2 + s3;
        int inc = sum;
        #pragma unroll
        for (int off = 1; off < 64; off <<= 1) {
            int uu = __shfl_up(inc, off, 64);
            if (lane >= off) inc += uu;
        }
        const int base = inc - sum;
        pre[rr][lane * 4 + 0] = base;
        pre[rr][lane * 4 + 1] = base + s0;
        pre[rr][lane * 4 + 2] = base + s0 + s1;
        pre[rr][lane * 4 + 3] = base + s0 + s1 + s2;
        if (lane == 63) pre[rr][NBUCK] = inc;    // = 384
    } else {
        // waves 1-5 -> p in [0,320); waves 7-11 -> p in [320,640); guard p<383
        const int p = (wave < 6) ? (wave - 1) * 64 + lane
                                 : 320 + (wave - 7) * 64 + lane;
        float a0 = 0.0f, a1 = 0.0f;
        if (p < MM) {
            const float invl = 1.0f / __builtin_amdgcn_logf((float)(p + 2));
            const int g0 = (p >= cum[0][0]) + (p >= cum[0][1]) + (p >= cum[0][2])
                         + (p >= cum[0][3]) + (p >= cum[0][4]);
            const int g1 = (p >= cum[1][0]) + (p >= cum[1][1]) + (p >= cum[1][2])
                         + (p >= cum[1][3]) + (p >= cum[1][4]);
            a0 = (float)((1 << (10 - g0)) - 1) * invl;
            a1 = (float)((1 << (10 - g1)) - 1) * invl;
        }
        #pragma unroll
        for (int off = 32; off > 0; off >>= 1) {
            a0 += __shfl_down(a0, off, 64);
            a1 += __shfl_down(a1, off, 64);
        }
        if (lane == 0) { idr[wave][0] = a0; idr[wave][1] = a1; }
    }
    __syncthreads();

    // ---- S4: scatter ----
    {
        const int pos = pre[r][b] + slot;
        vsort[r][pos] = vraw;
        sidx[r][pos]  = u;
    }
    __syncthreads();

    // ---- S5: soft window at sorted position u of row r ----
    const int   nrow  = n0 + r;
    const float ri    = vsort[r][u];
    const int   iorig = sidx[r][u];
    const float sn    = srow[r][nrow];

    int Blo = (int)((ri - WWIN) * BSCALE);
    int Bhi = (int)((ri + WWIN) * BSCALE);
    Blo = Blo < 0 ? 0 : (Blo > NBUCK - 1 ? NBUCK - 1 : Blo);
    Bhi = Bhi < 0 ? 0 : (Bhi > NBUCK - 1 ? NBUCK - 1 : Bhi);
    const int lo = pre[r][Blo];        // below: term ~ 0
    const int hi = pre[r][Bhi + 1];    // at/above: term ~ 1

    // pair-rcp: 1/(1+a) + 1/(1+b) = (2+(a+b)) * rcp(1+(a+b)+a*b)
    // window bounds |ri-v| <= ~18 => a,b <= 2.6e5, ab <= 7e10: fp32-safe.
    float acc = 0.0f;
    int q = lo;
    for (; q + 2 <= hi; q += 2) {
        float a  = __builtin_amdgcn_exp2f(ri - vsort[r][q]);
        float bb = __builtin_amdgcn_exp2f(ri - vsort[r][q + 1]);
        float e = a + bb;
        float f = a * bb;
        acc = fmaf(2.0f + e, __builtin_amdgcn_rcpf(1.0f + e + f), acc);
    }
    if (q < hi)
        acc += __builtin_amdgcn_rcpf(1.0f + __builtin_amdgcn_exp2f(ri - vsort[r][q]));
    float sum_all = (float)(NN - hi) + acc;

    // diagonal (c == nrow) correction, bucket-consistent with the window
    int bn = (int)(sn * BSCALE);
    bn = bn < 0 ? 0 : (bn > NBUCK - 1 ? NBUCK - 1 : bn);
    float cd = 0.0f;
    if (bn > Bhi)       cd = 1.0f;
    else if (bn >= Blo) cd = __builtin_amdgcn_rcpf(1.0f + __builtin_amdgcn_exp2f(ri - sn));
    // self term (sigma(0)=0.5) always in-window: ind = 1 + sum - 0.5 - cd
    const float ind = 0.5f + sum_all - cd;

    // ---- dcg term ----
    float dcg_i = 0.0f;
    if (iorig != nrow) {               // permutation covers all 383 real cols
        const int gd = gt[iorig] - gt[nrow];
        const int gg = gd < 0 ? -gd : gd;
        dcg_i = (float)((1 << (10 - gg)) - 1) / __builtin_amdgcn_logf(ind + 1.0f);
    }

    #pragma unroll
    for (int off = 32; off > 0; off >>= 1) dcg_i += __shfl_down(dcg_i, off, 64);
    if (lane == 0) redd[wave] = dcg_i;
    __syncthreads();

    // ---- S6: ndcg stores (idcg summed from per-wave partials) ----
    if (t == 0) {
        const float id = idr[1][0] + idr[2][0] + idr[3][0] + idr[4][0] + idr[5][0]
                       + idr[7][0] + idr[8][0] + idr[9][0] + idr[10][0] + idr[11][0];
        ndcg[n0] = (redd[0] + redd[1] + redd[2] + redd[3] + redd[4] + redd[5]) / id;
    }
    if (t == 384) {
        const float id = idr[1][1] + idr[2][1] + idr[3][1] + idr[4][1] + idr[5][1]
                       + idr[7][1] + idr[8][1] + idr[9][1] + idr[10][1] + idr[11][1];
        ndcg[n0 + 1] = (redd[6] + redd[7] + redd[8] + redd[9] + redd[10] + redd[11]) / id;
    }
}

__global__ __launch_bounds__(384) void dgc_final(const float* __restrict__ ndcg,
                                                 float* __restrict__ out) {
    __shared__ float red[6];
    const int t    = threadIdx.x;
    const int lane = t & 63;
    const int wave = t >> 6;
    float nd = ndcg[t];
    #pragma unroll
    for (int off = 32; off > 0; off >>= 1) nd += __shfl_down(nd, off, 64);
    if (lane == 0) red[wave] = nd;
    __syncthreads();
    if (t == 0) {
        float s = 0.0f;
        for (int w = 0; w < 6; ++w) s += red[w];
        out[0] = 1.0f - s / (float)NN;
    }
}

extern "C" void kernel_launch(void* const* d_in, const int* in_sizes, int n_in,
                              void* d_out, int out_size, void* d_ws, size_t ws_size,
                              hipStream_t stream) {
    const float* ranking = (const float*)d_in[0];
    const int*   gt      = (const int*)d_in[1];
    float*       out     = (float*)d_out;

    float* ndcg = (float*)d_ws;                  // 384 floats

    dgc_fused<<<NN / 2, 768, 0, stream>>>(ranking, gt, ndcg);
    dgc_final<<<1, 384, 0, stream>>>(ndcg, out);
}

// Round 2
// 69.813 us; speedup vs baseline: 1.1956x; 1.1956x over previous
//
#include <hip/hip_runtime.h>

// DGCLoss: 1 - mean NDCG. N=384 rows, D=256 feats, M=383 off-diag cols.
//
// Round 16: R14 coalesced-gram structure (R15's raw-row gram was a 64-line
// per-instr VMEM gather: +14us), with R15's validated tail ideas re-applied
// where they don't touch the load pattern:
//   - XN eliminated: fused scales the 2 center rows by invn_g at LDS-fill
//     (bit-identical to reading XN). dgc_trans loses a full pass + 384KB.
//   - idcg moved into dgc_fused (per-block cnt histogram overlapped with
//     gram; cum for the block's 2 gv values; p-loop on the 10 waves idle
//     during the hist scan). dgc_trans loses its tail block.
//   dgc_trans : 24 blocks: transpose+normalize -> XT[k][row], invn_g[row].
//   dgc_fused : block = rows (2b,2b+1): shared XT gram -> 2 srows, counting
//               sorts, pair-rcp soft window, per-block idcg, ndcg stores.
//   dgc_final : 1 block: out = 1 - mean(ndcg).

#define NN 384
#define DD 256
#define MM 383
// exp(-d*1000) == exp2(s_i - s_j) with s = ((cos+1)*0.5) * 1000*log2(e)
#define HSCALE 721.3475204444817f   // 0.5 * 1000 * log2(e)
#define NBUCK  256
#define BSCALE 0.1767955801104972f  // 256 / 1448  (values in [0, 1442.7])
#define WWIN   6.0f                 // soft-window half-width in s-units

__global__ __launch_bounds__(256) void dgc_trans(const float* __restrict__ x,
                                                 float* __restrict__ XT,
                                                 float* __restrict__ invn_g) {
    __shared__ float xs[16][260];   // +4 pad: conflict-free
    __shared__ float invn[16];
    const int t  = threadIdx.x;
    const int r0 = blockIdx.x * 16;

    #pragma unroll
    for (int i = 0; i < 4; ++i) {
        int f = t + i * 256;            // float4 unit 0..1023
        int r = f >> 6, c4 = f & 63;
        float4 v = ((const float4*)(x + (size_t)(r0 + r) * DD))[c4];
        xs[r][c4 * 4 + 0] = v.x; xs[r][c4 * 4 + 1] = v.y;
        xs[r][c4 * 4 + 2] = v.z; xs[r][c4 * 4 + 3] = v.w;
    }
    __syncthreads();

    {   // row norms: 16 threads per row
        const int r = t >> 4, sub = t & 15;
        float s = 0.0f;
        #pragma unroll
        for (int m = 0; m < 16; ++m) {
            float v = xs[r][sub * 16 + m];
            s = fmaf(v, v, s);
        }
        #pragma unroll
        for (int off = 8; off > 0; off >>= 1) s += __shfl_xor(s, off, 64);
        if (sub == 0) invn[r] = __builtin_amdgcn_rsqf(fmaxf(s, 1e-16f));
    }
    __syncthreads();

    if (t < 16) invn_g[r0 + t] = invn[t];

    {   // normalized transpose XT[k][r0+r]
        const int r  = t & 15;
        const int kk = t >> 4;
        const float inv = invn[r];
        #pragma unroll
        for (int i = 0; i < 16; ++i) {
            int k = i * 16 + kk;
            XT[(size_t)k * NN + r0 + r] = xs[r][k] * inv;
        }
    }
}

__global__ __launch_bounds__(768) void dgc_fused(const float* __restrict__ XT,
                                                 const float* __restrict__ x,
                                                 const float* __restrict__ invn_g,
                                                 const int* __restrict__ gt,
                                                 float* __restrict__ ndcg) {
    __shared__ float  xs[2][DD];        // normalized rows n0, n0+1
    __shared__ float4 pacc[2][8][96];   // [row][k-chunk][j4] partial dots
    __shared__ float  srow[2][NN];
    __shared__ float  vsort[2][NN];
    __shared__ int    sidx[2][NN];
    __shared__ int    hist[2][NBUCK];
    __shared__ int    pre[2][NBUCK + 1];
    __shared__ int    cnt[6];
    __shared__ int    cum[2][6];
    __shared__ float  redd[12];
    __shared__ float  idr[12][2];       // per-wave idcg partials (waves 0,6 stay 0)

    const int n0   = blockIdx.x * 2;
    const int t    = threadIdx.x;
    const int lane = t & 63;
    const int wave = t >> 6;

    // ---- S0: init ----
    if (t < 128) {
        const int rr = t >> 6;
        const float inv = invn_g[n0 + rr];
        float4 v = ((const float4*)(x + (size_t)(n0 + rr) * DD))[t & 63];
        v.x *= inv; v.y *= inv; v.z *= inv; v.w *= inv;
        ((float4*)xs[rr])[t & 63] = v;
    }
    if (t < 512) ((int*)hist)[t] = 0;
    if (t < 6)  cnt[t] = 0;
    if (t < 24) ((float*)idr)[t] = 0.0f;
    __syncthreads();

    // ---- S1: gt histogram (overlaps gram) + gram into pacc ----
    if (t < NN) atomicAdd(&cnt[gt[t]], 1);

    {   // j4 = t%96 (4 cols), kc = t/96 (8 chunks of 32 k's).
        const int j4 = t % 96;
        const int kc = t / 96;                 // 0..7
        const float4* XT4 = (const float4*)XT;
        float4 a0 = {0.f, 0.f, 0.f, 0.f};
        float4 a1 = {0.f, 0.f, 0.f, 0.f};
        const int k0 = kc * 32;
        #pragma unroll 8
        for (int m = 0; m < 32; ++m) {
            const int k = k0 + m;
            float4 b = XT4[(size_t)k * 96 + j4];   // coalesced, loaded once
            float s0 = xs[0][k];
            float s1 = xs[1][k];
            a0.x = fmaf(s0, b.x, a0.x); a0.y = fmaf(s0, b.y, a0.y);
            a0.z = fmaf(s0, b.z, a0.z); a0.w = fmaf(s0, b.w, a0.w);
            a1.x = fmaf(s1, b.x, a1.x); a1.y = fmaf(s1, b.y, a1.y);
            a1.z = fmaf(s1, b.z, a1.z); a1.w = fmaf(s1, b.w, a1.w);
        }
        pacc[0][kc][j4] = a0;
        pacc[1][kc][j4] = a1;
    }
    __syncthreads();

    const int r = t / 384;                 // row-half: waves 0-5 -> 0, 6-11 -> 1
    const int u = t - r * 384;             // 0..383

    // ---- S2: cum tables (threads 0,1) + reduce pacc + bucket ----
    if (t < 2) {
        const int gv = gt[n0 + t];
        int h[6];
        #pragma unroll
        for (int g = 0; g < 6; ++g) h[g] = 0;
        #pragma unroll
        for (int v = 0; v < 6; ++v) {
            int d = v - gv; d = d < 0 ? -d : d;
            h[d] += cnt[v];
        }
        h[0] -= 1;                         // remove self term
        int s = 0;
        #pragma unroll
        for (int g = 0; g < 6; ++g) { s += h[g]; cum[t][g] = s; }
    }

    {   // reduce 8 k-chunks; flat float view per row: [kc*384 + u]
        const float* pf = (const float*)pacc[r];
        float dot = 0.0f;
        #pragma unroll
        for (int c = 0; c < 8; ++c) dot += pf[c * 384 + u];
        srow[r][u] = fmaf(dot, HSCALE, HSCALE);
    }
    __syncthreads();

    // ---- counting sort per row ----
    const float vraw = srow[r][u];
    int b = (int)(vraw * BSCALE);
    b = b < 0 ? 0 : (b > NBUCK - 1 ? NBUCK - 1 : b);
    const int slot = atomicAdd(&hist[r][b], 1);
    __syncthreads();

    // ---- S3: hist scan (waves 0,6) || per-block idcg p-loop (other waves) ----
    if (wave == 0 || wave == 6) {
        const int rr = wave / 6;
        const int s0 = hist[rr][lane * 4 + 0], s1 = hist[rr][lane * 4 + 1];
        const int s2 = hist[rr][lane * 4 + 2], s3 = hist[rr][lane * 4 + 3];
        const int sum = s0 + s1 + s2 + s3;
        int inc = sum;
        #pragma unroll
        for (int off = 1; off < 64; off <<= 1) {
            int uu = __shfl_up(inc, off, 64);
            if (lane >= off) inc += uu;
        }
        const int base = inc - sum;
        pre[rr][lane * 4 + 0] = base;
        pre[rr][lane * 4 + 1] = base + s0;
        pre[rr][lane * 4 + 2] = base + s0 + s1;
        pre[rr][lane * 4 + 3] = base + s0 + s1 + s2;
        if (lane == 63) pre[rr][NBUCK] = inc;    // = 384
    } else {
        // waves 1-5 -> p in [0,320); waves 7-11 -> p in [320,640); guard p<383
        const int p = (wave < 6) ? (wave - 1) * 64 + lane
                                 : 320 + (wave - 7) * 64 + lane;
        float a0 = 0.0f, a1 = 0.0f;
        if (p < MM) {
            const float invl = 1.0f / __builtin_amdgcn_logf((float)(p + 2));
            const int g0 = (p >= cum[0][0]) + (p >= cum[0][1]) + (p >= cum[0][2])
                         + (p >= cum[0][3]) + (p >= cum[0][4]);
            const int g1 = (p >= cum[1][0]) + (p >= cum[1][1]) + (p >= cum[1][2])
                         + (p >= cum[1][3]) + (p >= cum[1][4]);
            a0 = (float)((1 << (10 - g0)) - 1) * invl;
            a1 = (float)((1 << (10 - g1)) - 1) * invl;
        }
        #pragma unroll
        for (int off = 32; off > 0; off >>= 1) {
            a0 += __shfl_down(a0, off, 64);
            a1 += __shfl_down(a1, off, 64);
        }
        if (lane == 0) { idr[wave][0] = a0; idr[wave][1] = a1; }
    }
    __syncthreads();

    // ---- S4: scatter ----
    {
        const int pos = pre[r][b] + slot;
        vsort[r][pos] = vraw;
        sidx[r][pos]  = u;
    }
    __syncthreads();

    // ---- S5: soft window at sorted position u of row r ----
    const int   nrow  = n0 + r;
    const float ri    = vsort[r][u];
    const int   iorig = sidx[r][u];
    const float sn    = srow[r][nrow];

    int Blo = (int)((ri - WWIN) * BSCALE);
    int Bhi = (int)((ri + WWIN) * BSCALE);
    Blo = Blo < 0 ? 0 : (Blo > NBUCK - 1 ? NBUCK - 1 : Blo);
    Bhi = Bhi < 0 ? 0 : (Bhi > NBUCK - 1 ? NBUCK - 1 : Bhi);
    const int lo = pre[r][Blo];        // below: term ~ 0
    const int hi = pre[r][Bhi + 1];    // at/above: term ~ 1

    // pair-rcp: 1/(1+a) + 1/(1+b) = (2+(a+b)) * rcp(1+(a+b)+a*b)
    // window bounds |ri-v| <= ~18 => a,b <= 2.6e5, ab <= 7e10: fp32-safe.
    float acc = 0.0f;
    int q = lo;
    for (; q + 2 <= hi; q += 2) {
        float a  = __builtin_amdgcn_exp2f(ri - vsort[r][q]);
        float bb = __builtin_amdgcn_exp2f(ri - vsort[r][q + 1]);
        float e = a + bb;
        float f = a * bb;
        acc = fmaf(2.0f + e, __builtin_amdgcn_rcpf(1.0f + e + f), acc);
    }
    if (q < hi)
        acc += __builtin_amdgcn_rcpf(1.0f + __builtin_amdgcn_exp2f(ri - vsort[r][q]));
    float sum_all = (float)(NN - hi) + acc;

    // diagonal (c == nrow) correction, bucket-consistent with the window
    int bn = (int)(sn * BSCALE);
    bn = bn < 0 ? 0 : (bn > NBUCK - 1 ? NBUCK - 1 : bn);
    float cd = 0.0f;
    if (bn > Bhi)       cd = 1.0f;
    else if (bn >= Blo) cd = __builtin_amdgcn_rcpf(1.0f + __builtin_amdgcn_exp2f(ri - sn));
    // self term (sigma(0)=0.5) always in-window: ind = 1 + sum - 0.5 - cd
    const float ind = 0.5f + sum_all - cd;

    // ---- dcg term ----
    float dcg_i = 0.0f;
    if (iorig != nrow) {               // permutation covers all 383 real cols
        const int gd = gt[iorig] - gt[nrow];
        const int gg = gd < 0 ? -gd : gd;
        dcg_i = (float)((1 << (10 - gg)) - 1) / __builtin_amdgcn_logf(ind + 1.0f);
    }

    #pragma unroll
    for (int off = 32; off > 0; off >>= 1) dcg_i += __shfl_down(dcg_i, off, 64);
    if (lane == 0) redd[wave] = dcg_i;
    __syncthreads();

    // ---- S6: ndcg stores (idcg summed from per-wave partials) ----
    if (t == 0) {
        const float id = idr[1][0] + idr[2][0] + idr[3][0] + idr[4][0] + idr[5][0]
                       + idr[7][0] + idr[8][0] + idr[9][0] + idr[10][0] + idr[11][0];
        ndcg[n0] = (redd[0] + redd[1] + redd[2] + redd[3] + redd[4] + redd[5]) / id;
    }
    if (t == 384) {
        const float id = idr[1][1] + idr[2][1] + idr[3][1] + idr[4][1] + idr[5][1]
                       + idr[7][1] + idr[8][1] + idr[9][1] + idr[10][1] + idr[11][1];
        ndcg[n0 + 1] = (redd[6] + redd[7] + redd[8] + redd[9] + redd[10] + redd[11])
                       / id;
    }
}

__global__ __launch_bounds__(384) void dgc_final(const float* __restrict__ ndcg,
                                                 float* __restrict__ out) {
    __shared__ float red[6];
    const int t    = threadIdx.x;
    const int lane = t & 63;
    const int wave = t >> 6;
    float nd = ndcg[t];
    #pragma unroll
    for (int off = 32; off > 0; off >>= 1) nd += __shfl_down(nd, off, 64);
    if (lane == 0) red[wave] = nd;
    __syncthreads();
    if (t == 0) {
        float s = 0.0f;
        for (int w = 0; w < 6; ++w) s += red[w];
        out[0] = 1.0f - s / (float)NN;
    }
}

extern "C" void kernel_launch(void* const* d_in, const int* in_sizes, int n_in,
                              void* d_out, int out_size, void* d_ws, size_t ws_size,
                              hipStream_t stream) {
    const float* ranking = (const float*)d_in[0];
    const int*   gt      = (const int*)d_in[1];
    float*       out     = (float*)d_out;

    float* XT     = (float*)d_ws;                // 256*384
    float* invn_g = XT + (size_t)DD * NN;        // 384
    float* ndcg   = invn_g + NN;                 // 384

    dgc_trans<<<24, 256, 0, stream>>>(ranking, XT, invn_g);
    dgc_fused<<<NN / 2, 768, 0, stream>>>(XT, ranking, invn_g, gt, ndcg);
    dgc_final<<<1, 384, 0, stream>>>(ndcg, out);
}